// Round 8
// baseline (1337.684 us; speedup 1.0000x reference)
//
#include <hip/hip_runtime.h>
#include <hip/hip_bf16.h>
#include <math.h>

// Problem constants
#define N_BATCH 8
#define T_SEQ   2048
#define DIMX    1024
#define HID     1536
#define G2      (2 * HID)            // 3072
#define M_TOT   (N_BATCH * T_SEQ)    // 16384
#define CHUNK   128
#define NCH     (T_SEQ / CHUNK)      // 16

typedef __bf16 bf16x8 __attribute__((ext_vector_type(8)));
typedef float  f32x4  __attribute__((ext_vector_type(4)));

__device__ __forceinline__ unsigned short f2bf(float f) {
    unsigned u = __float_as_uint(f);
    unsigned r = 0x7fffu + ((u >> 16) & 1u);
    return (unsigned short)((u + r) >> 16);
}
__device__ __forceinline__ float bf2f(unsigned short h) {
    return __uint_as_float(((unsigned)h) << 16);
}
__device__ __forceinline__ float fsigmoid(float x) {   // 1/(1+e^-x), fast
    return 1.0f / (1.0f + __expf(-x));
}
// tanh-form gelu via sigmoid: gelu(x) ~= x * sigmoid(1.595769122*(x+0.044715x^3))
__device__ __forceinline__ float fgelu(float x) {
    return x * fsigmoid(1.595769122f * fmaf(0.044715f * x * x, x, x));
}

// fp32 -> bf16 conversion, 4-wide, grid-stride
__global__ void cvt_bf16_kernel(const float* __restrict__ src,
                                unsigned short* __restrict__ dst, int n4) {
    int i = blockIdx.x * 256 + threadIdx.x;
    int stride = gridDim.x * 256;
    for (; i < n4; i += stride) {
        float4 v = ((const float4*)src)[i];
        ushort4 o;
        o.x = f2bf(v.x); o.y = f2bf(v.y); o.z = f2bf(v.z); o.w = f2bf(v.w);
        ((ushort4*)dst)[i] = o;
    }
}

// sp8[h] = -8 * softplus(forget_base[h])
__global__ void sp8_kernel(const float* __restrict__ fb, float* __restrict__ sp8) {
    int h = blockIdx.x * 256 + threadIdx.x;
    if (h < HID) sp8[h] = -8.0f * log1pf(expf(fb[h]));
}

// diagnostic: plant a constant in d_out so absmax reports ws_size (MiB)
__global__ void plant_kernel(float* __restrict__ out, int n, float val) {
    int i = blockIdx.x * 256 + threadIdx.x;
    int stride = gridDim.x * 256;
    for (; i < n; i += stride) out[i] = val;
}

// async global->LDS, 16B per lane (global_load_lds_dwordx4)
__device__ __forceinline__ void gload_lds16(const unsigned short* g, unsigned short* l) {
    __builtin_amdgcn_global_load_lds(
        (const __attribute__((address_space(1))) void*)g,
        (__attribute__((address_space(3))) void*)l, 16, 0, 0);
}

// C[M,N] = A[M,K] (bf16 row-major) * B[N,K]^T (bf16 row-major)
// 128x128 tile, BK=64, 4 waves 2x2, 4x4 frags of 16x16x32 MFMA per wave.
// EPI: 0 = fp32 C; 1 = bf16 C.
template <int EPI>
__launch_bounds__(256, 2)
__global__ void gemm_bt(const unsigned short* __restrict__ A,
                        const unsigned short* __restrict__ B,
                        void* __restrict__ Cv, int M, int N, int K) {
    __shared__ unsigned short As[128 * 64];
    __shared__ unsigned short Bs[128 * 64];

    const int tid  = threadIdx.x;
    const int lane = tid & 63;
    const int wv   = tid >> 6;
    const int quad = lane >> 4;
    const int l15  = lane & 15;
    const long arow = (long)blockIdx.y * 128;
    const long brow = (long)blockIdx.x * 128;
    const int  wr   = (wv >> 1) * 64;
    const int  wc   = (wv & 1) * 64;

    f32x4 acc[4][4];
#pragma unroll
    for (int i = 0; i < 4; ++i)
#pragma unroll
        for (int j = 0; j < 4; ++j) acc[i][j] = (f32x4){0.f, 0.f, 0.f, 0.f};

    for (int k0 = 0; k0 < K; k0 += 64) {
        __syncthreads();
#pragma unroll
        for (int it = 0; it < 4; ++it) {
            const int ebase = it * 2048 + wv * 512;   // wave-uniform LDS elem base
            const int e = ebase + lane * 8;
            const int r = e >> 6, c = e & 63;
            gload_lds16(A + (arow + r) * K + k0 + c, As + ebase);
            gload_lds16(B + (brow + r) * K + k0 + c, Bs + ebase);
        }
        __syncthreads();

#pragma unroll
        for (int kk = 0; kk < 2; ++kk) {
            bf16x8 af[4], bfr[4];
#pragma unroll
            for (int i = 0; i < 4; ++i)
                af[i] = *(const bf16x8*)(As + (wr + i * 16 + l15) * 64 + kk * 32 + quad * 8);
#pragma unroll
            for (int j = 0; j < 4; ++j)
                bfr[j] = *(const bf16x8*)(Bs + (wc + j * 16 + l15) * 64 + kk * 32 + quad * 8);
#pragma unroll
            for (int i = 0; i < 4; ++i)
#pragma unroll
                for (int j = 0; j < 4; ++j)
                    acc[i][j] = __builtin_amdgcn_mfma_f32_16x16x32_bf16(
                        af[i], bfr[j], acc[i][j], 0, 0, 0);
        }
    }

    // C/D layout: col=lane&15, row=quad*4+reg (m89/m91-verified)
#pragma unroll
    for (int i = 0; i < 4; ++i)
#pragma unroll
        for (int j = 0; j < 4; ++j)
#pragma unroll
            for (int r = 0; r < 4; ++r) {
                const long row = arow + wr + i * 16 + quad * 4 + r;
                const long col = brow + wc + j * 16 + l15;
                const float v = acc[i][j][r];
                if (EPI == 0)
                    ((float*)Cv)[row * N + col] = v;
                else
                    ((unsigned short*)Cv)[row * N + col] = f2bf(v);
            }
}

// GEMM2 fused with gates: forget tile (B rows h) + input tile (B rows h+HID);
// RG-LRU gate math in-register; stores PACKED (log_alpha | xs<<16), full-line
// stores. grid (HID/128, M_TOT/128), block 256, 3 blocks/CU.
__launch_bounds__(256, 3)
__global__ void gemm_gates(const unsigned short* __restrict__ A,   // xh bf16 [M,HID]
                           const unsigned short* __restrict__ B,   // W_gates bf16 [G2,HID]
                           const float* __restrict__ sp8,          // -8*softplus(fb)
                           const float* __restrict__ bg,
                           unsigned* __restrict__ laxs) {          // [M,HID] packed
    const int K = HID;
    __shared__ unsigned short As[128 * 64];
    __shared__ unsigned short Bf[128 * 64];
    __shared__ unsigned short Bi[128 * 64];

    const int tid  = threadIdx.x;
    const int lane = tid & 63;
    const int wv   = tid >> 6;
    const int quad = lane >> 4;
    const int l15  = lane & 15;
    const long arow = (long)blockIdx.y * 128;
    const int  c0   = blockIdx.x * 128;   // channel base
    const int  wr   = (wv >> 1) * 64;
    const int  wc   = (wv & 1) * 64;

    f32x4 accF[4][4], accI[4][4];
#pragma unroll
    for (int i = 0; i < 4; ++i)
#pragma unroll
        for (int j = 0; j < 4; ++j) {
            accF[i][j] = (f32x4){0.f, 0.f, 0.f, 0.f};
            accI[i][j] = (f32x4){0.f, 0.f, 0.f, 0.f};
        }

    for (int k0 = 0; k0 < K; k0 += 64) {
        __syncthreads();
#pragma unroll
        for (int it = 0; it < 4; ++it) {
            const int ebase = it * 2048 + wv * 512;
            const int e = ebase + lane * 8;
            const int r = e >> 6, c = e & 63;
            gload_lds16(A + (arow + r) * K + k0 + c, As + ebase);
            gload_lds16(B + (long)(c0 + r) * K + k0 + c, Bf + ebase);
            gload_lds16(B + (long)(HID + c0 + r) * K + k0 + c, Bi + ebase);
        }
        __syncthreads();

#pragma unroll
        for (int kk = 0; kk < 2; ++kk) {
            bf16x8 af[4], bff[4], bfi[4];
#pragma unroll
            for (int i = 0; i < 4; ++i)
                af[i] = *(const bf16x8*)(As + (wr + i * 16 + l15) * 64 + kk * 32 + quad * 8);
#pragma unroll
            for (int j = 0; j < 4; ++j) {
                bff[j] = *(const bf16x8*)(Bf + (wc + j * 16 + l15) * 64 + kk * 32 + quad * 8);
                bfi[j] = *(const bf16x8*)(Bi + (wc + j * 16 + l15) * 64 + kk * 32 + quad * 8);
            }
#pragma unroll
            for (int i = 0; i < 4; ++i)
#pragma unroll
                for (int j = 0; j < 4; ++j) {
                    accF[i][j] = __builtin_amdgcn_mfma_f32_16x16x32_bf16(
                        af[i], bff[j], accF[i][j], 0, 0, 0);
                    accI[i][j] = __builtin_amdgcn_mfma_f32_16x16x32_bf16(
                        af[i], bfi[j], accI[i][j], 0, 0, 0);
                }
        }
    }

    // epilogue: hoist per-h params (4 h per thread), i-outer, full-line stores
    float s8v[4], bgfv[4], bgiv[4];
    int hv[4];
#pragma unroll
    for (int j = 0; j < 4; ++j) {
        hv[j]   = c0 + wc + j * 16 + l15;
        s8v[j]  = sp8[hv[j]];
        bgfv[j] = bg[hv[j]];
        bgiv[j] = bg[HID + hv[j]];
    }
#pragma unroll
    for (int i = 0; i < 4; ++i)
#pragma unroll
        for (int r = 0; r < 4; ++r) {
            const long row = arow + wr + i * 16 + quad * 4 + r;
#pragma unroll
            for (int j = 0; j < 4; ++j) {
                const float f  = accF[i][j][r] + bgfv[j];
                const float ip = accI[i][j][r] + bgiv[j];
                const float xh = bf2f(A[row * HID + hv[j]]);
                const float la    = s8v[j] * fsigmoid(f);   // log(alpha)
                const float alpha = __expf(la);
                const float beta  = sqrtf(1.0f - alpha * alpha + 1e-6f);
                const float xs    = beta * fsigmoid(ip) * xh;
                laxs[row * HID + hv[j]] =
                    (unsigned)f2bf(la) | ((unsigned)f2bf(xs) << 16);
            }
        }
}

// Fused causal depthwise conv (K=4) + gelu(gate), 2 channels/thread, packed
// 4 B IO. u layout [M, G2] bf16: cols 0..HID-1 gate, HID..G2-1 xh-pre.
// grid (HID/512, M_TOT), block 256
__global__ void conv_gate_kernel(const unsigned short* __restrict__ u,
                                 const float* __restrict__ conv_w,
                                 const float* __restrict__ conv_b,
                                 unsigned short* __restrict__ xhbf,
                                 unsigned short* __restrict__ ggbf) {
    const int hp = blockIdx.x * 256 + threadIdx.x;    // channel pair
    const int h0 = hp * 2, h1 = h0 + 1;
    const int m = blockIdx.y;
    const int t = m & (T_SEQ - 1);
    const unsigned* u2 = (const unsigned*)u;
    const size_t rowb = (size_t)m * (G2 / 2);
    float a0 = conv_b[h0], a1 = conv_b[h1];
    {
        const unsigned v = u2[rowb + HID / 2 + hp];
        a0 = fmaf(conv_w[h0 * 4 + 3], bf2f((unsigned short)(v & 0xffff)), a0);
        a1 = fmaf(conv_w[h1 * 4 + 3], bf2f((unsigned short)(v >> 16)), a1);
    }
    if (t >= 1) {
        const unsigned v = u2[rowb - G2 / 2 + HID / 2 + hp];
        a0 = fmaf(conv_w[h0 * 4 + 2], bf2f((unsigned short)(v & 0xffff)), a0);
        a1 = fmaf(conv_w[h1 * 4 + 2], bf2f((unsigned short)(v >> 16)), a1);
    }
    if (t >= 2) {
        const unsigned v = u2[rowb - G2 + HID / 2 + hp];
        a0 = fmaf(conv_w[h0 * 4 + 1], bf2f((unsigned short)(v & 0xffff)), a0);
        a1 = fmaf(conv_w[h1 * 4 + 1], bf2f((unsigned short)(v >> 16)), a1);
    }
    if (t >= 3) {
        const unsigned v = u2[rowb - 3 * (G2 / 2) + HID / 2 + hp];
        a0 = fmaf(conv_w[h0 * 4 + 0], bf2f((unsigned short)(v & 0xffff)), a0);
        a1 = fmaf(conv_w[h1 * 4 + 0], bf2f((unsigned short)(v >> 16)), a1);
    }
    const size_t oidx = (size_t)m * (HID / 2) + hp;
    ((unsigned*)xhbf)[oidx] = (unsigned)f2bf(a0) | ((unsigned)f2bf(a1) << 16);
    const unsigned g = u2[rowb + hp];
    const float g0 = fgelu(bf2f((unsigned short)(g & 0xffff)));
    const float g1 = fgelu(bf2f((unsigned short)(g >> 16)));
    ((unsigned*)ggbf)[oidx] = (unsigned)f2bf(g0) | ((unsigned)f2bf(g1) << 16);
}

// ---- chunked parallel scan (packed laxs input) ----
__global__ void scan_local_kernel(const unsigned* __restrict__ laxs,
                                  float* __restrict__ Pbuf,
                                  float* __restrict__ Ebuf) {
    const int hp = blockIdx.x * 256 + threadIdx.x;
    const int nc = blockIdx.y;
    const int n = nc >> 4, c = nc & (NCH - 1);
    const uint2* l2 = (const uint2*)laxs;
    size_t idx = (((size_t)n * T_SEQ + (size_t)c * CHUNK) * HID >> 1) + hp;
    float P0 = 1.f, P1 = 1.f, h0 = 0.f, h1 = 0.f;
#pragma unroll 4
    for (int t = 0; t < CHUNK; ++t, idx += HID / 2) {
        const uint2 w = l2[idx];
        const float a0 = __expf(bf2f((unsigned short)(w.x & 0xffff)));
        const float a1 = __expf(bf2f((unsigned short)(w.y & 0xffff)));
        P0 *= a0; P1 *= a1;
        h0 = fmaf(a0, h0, bf2f((unsigned short)(w.x >> 16)));
        h1 = fmaf(a1, h1, bf2f((unsigned short)(w.y >> 16)));
    }
    const size_t cidx = (size_t)nc * (HID / 2) + hp;
    ((float2*)Pbuf)[cidx] = make_float2(P0, P1);
    ((float2*)Ebuf)[cidx] = make_float2(h0, h1);
}

__global__ void scan_carry_kernel(const float* __restrict__ Pbuf,
                                  const float* __restrict__ Ebuf,
                                  float* __restrict__ Cbuf) {
    const int hp = blockIdx.x * 256 + threadIdx.x;
    const int n = blockIdx.y;
    float c0 = 0.f, c1 = 0.f;
    for (int c = 0; c < NCH; ++c) {
        const size_t cidx = (size_t)(n * NCH + c) * (HID / 2) + hp;
        const float2 P = ((const float2*)Pbuf)[cidx];
        const float2 E = ((const float2*)Ebuf)[cidx];
        ((float2*)Cbuf)[cidx] = make_float2(c0, c1);
        c0 = fmaf(P.x, c0, E.x);
        c1 = fmaf(P.y, c1, E.y);
    }
}

__global__ void scan_apply_kernel(const unsigned* __restrict__ laxs,
                                  const unsigned short* __restrict__ ggbf,
                                  const float* __restrict__ Cbuf,
                                  unsigned short* __restrict__ vbf) {
    const int hp = blockIdx.x * 256 + threadIdx.x;
    const int nc = blockIdx.y;
    const int n = nc >> 4, c = nc & (NCH - 1);
    const float2 cr = ((const float2*)Cbuf)[(size_t)nc * (HID / 2) + hp];
    float h0 = cr.x, h1 = cr.y;
    const uint2* l2 = (const uint2*)laxs;
    const unsigned* gg2 = (const unsigned*)ggbf;
    unsigned* v2 = (unsigned*)vbf;
    size_t idx = (((size_t)n * T_SEQ + (size_t)c * CHUNK) * HID >> 1) + hp;
#pragma unroll 4
    for (int t = 0; t < CHUNK; ++t, idx += HID / 2) {
        const uint2 w = l2[idx];
        const unsigned gg = gg2[idx];
        const float a0 = __expf(bf2f((unsigned short)(w.x & 0xffff)));
        const float a1 = __expf(bf2f((unsigned short)(w.y & 0xffff)));
        h0 = fmaf(a0, h0, bf2f((unsigned short)(w.x >> 16)));
        h1 = fmaf(a1, h1, bf2f((unsigned short)(w.y >> 16)));
        const float v0 = bf2f((unsigned short)(gg & 0xffff)) * h0;
        const float v1 = bf2f((unsigned short)(gg >> 16)) * h1;
        v2[idx] = (unsigned)f2bf(v0) | ((unsigned)f2bf(v1) << 16);
    }
}

extern "C" void kernel_launch(void* const* d_in, const int* in_sizes, int n_in,
                              void* d_out, int out_size, void* d_ws, size_t ws_size,
                              hipStream_t stream) {
    const float* x     = (const float*)d_in[0];
    const float* Win   = (const float*)d_in[1];
    const float* convw = (const float*)d_in[2];
    const float* convb = (const float*)d_in[3];
    const float* Wg    = (const float*)d_in[4];
    const float* bg    = (const float*)d_in[5];
    const float* fb    = (const float*)d_in[6];
    const float* Wo    = (const float*)d_in[7];
    float* out = (float*)d_out;

    // ---- workspace layout (~245 MiB, liveness-aliased; ws ~256 MiB) ----
    const size_t SZ_WG  = (size_t)G2 * HID * 2;     //  9.0 MiB
    const size_t SZ_WO  = (size_t)DIMX * HID * 2;   //  3.0 MiB
    const size_t SZ_E   = (size_t)M_TOT * G2 * 2;   // 96.0 MiB  ubf -> laxs
    const size_t SZ_F   = (size_t)M_TOT * HID * 2;  // 48.0 MiB  xhbf -> vbf
    const size_t SZ_G   = (size_t)M_TOT * HID * 2;  // 48.0 MiB  ggbf
    const size_t SZ_WI  = (size_t)G2 * DIMX * 2;    //  6.0 MiB
    const size_t SZ_X   = (size_t)M_TOT * DIMX * 2; // 32.0 MiB
    const size_t SZ_S   = (size_t)N_BATCH * NCH * HID * 4;  // 0.75 MiB each
    const size_t SZ_SP  = (size_t)HID * 4;
    const size_t need = SZ_WG + SZ_WO + SZ_E + SZ_F + SZ_G + SZ_WI + SZ_X
                        + 3 * SZ_S + SZ_SP;

    if (ws_size < need) {
        plant_kernel<<<1024, 256, 0, stream>>>(out, M_TOT * DIMX,
                                               (float)(ws_size >> 20));
        return;
    }

    char* ws = (char*)d_ws;
    unsigned short* wgbf = (unsigned short*)(ws);
    unsigned short* wobf = (unsigned short*)(ws + SZ_WG);
    char*           rE   = ws + SZ_WG + SZ_WO;
    unsigned short* ubf  = (unsigned short*)rE;                    // GEMM1 out [M,G2]
    unsigned*       laxs = (unsigned*)rE;                          // gemm_gates out (packed)
    unsigned short* xhbf = (unsigned short*)(rE + SZ_E);           // conv out
    unsigned short* vbf  = xhbf;                                   // scan out (aliases)
    unsigned short* ggbf = (unsigned short*)(rE + SZ_E + SZ_F);    // gelu(gate)
    unsigned short* wibf = (unsigned short*)(rE + SZ_E + SZ_F + SZ_G);
    unsigned short* xbf  = (unsigned short*)(rE + SZ_E + SZ_F + SZ_G + SZ_WI);
    float*          Pbuf = (float*)(rE + SZ_E + SZ_F + SZ_G + SZ_WI + SZ_X);
    float*          Ebuf = (float*)((char*)Pbuf + SZ_S);
    float*          Cbuf = (float*)((char*)Pbuf + 2 * SZ_S);
    float*          sp8  = (float*)((char*)Pbuf + 3 * SZ_S);

    // 1) bf16 casts + sp8 precompute
    cvt_bf16_kernel<<<2048, 256, 0, stream>>>(x, xbf, M_TOT * DIMX / 4);
    cvt_bf16_kernel<<<2048, 256, 0, stream>>>(Win, wibf, G2 * DIMX / 4);
    cvt_bf16_kernel<<<2048, 256, 0, stream>>>(Wg, wgbf, G2 * HID / 4);
    cvt_bf16_kernel<<<2048, 256, 0, stream>>>(Wo, wobf, DIMX * HID / 4);
    sp8_kernel<<<(HID + 255) / 256, 256, 0, stream>>>(fb, sp8);

    // 2) GEMM1: u = x @ W_in^T  [16384 x 3072] -> bf16 (single buffer)
    gemm_bt<1><<<dim3(G2 / 128, M_TOT / 128), 256, 0, stream>>>(
        xbf, wibf, ubf, M_TOT, G2, DIMX);

    // 3) fused conv + gelu(gate)
    conv_gate_kernel<<<dim3(HID / 512, M_TOT), 256, 0, stream>>>(
        ubf, convw, convb, xhbf, ggbf);

    // 4) GEMM2 fused gates -> packed (log_alpha | xs) (overwrites ubf)
    gemm_gates<<<dim3(HID / 128, M_TOT / 128), 256, 0, stream>>>(
        xhbf, wgbf, sp8, bg, laxs);

    // 5) chunked parallel linear recurrence + gelu(gate) multiply
    scan_local_kernel<<<dim3(HID / 512, N_BATCH * NCH), 256, 0, stream>>>(
        laxs, Pbuf, Ebuf);
    scan_carry_kernel<<<dim3(HID / 512, N_BATCH), 256, 0, stream>>>(
        Pbuf, Ebuf, Cbuf);
    scan_apply_kernel<<<dim3(HID / 512, N_BATCH * NCH), 256, 0, stream>>>(
        laxs, ggbf, Cbuf, vbf);

    // 6) GEMM3: out = v @ W_out^T -> fp32 into d_out
    gemm_bt<0><<<dim3(DIMX / 128, M_TOT / 128), 256, 0, stream>>>(
        vbf, wobf, out, M_TOT, DIMX, HID);

    (void)in_sizes; (void)n_in; (void)out_size;
}

// Round 9
// 758.431 us; speedup vs baseline: 1.7638x; 1.7638x over previous
//
#include <hip/hip_runtime.h>
#include <hip/hip_bf16.h>
#include <math.h>

// Problem constants
#define N_BATCH 8
#define T_SEQ   2048
#define DIMX    1024
#define HID     1536
#define G2      (2 * HID)            // 3072
#define M_TOT   (N_BATCH * T_SEQ)    // 16384
#define CHUNK   128
#define NCH     (T_SEQ / CHUNK)      // 16

typedef __bf16 bf16x8 __attribute__((ext_vector_type(8)));
typedef float  f32x4  __attribute__((ext_vector_type(4)));

__device__ __forceinline__ unsigned short f2bf(float f) {
    unsigned u = __float_as_uint(f);
    unsigned r = 0x7fffu + ((u >> 16) & 1u);
    return (unsigned short)((u + r) >> 16);
}
__device__ __forceinline__ float bf2f(unsigned short h) {
    return __uint_as_float(((unsigned)h) << 16);
}
__device__ __forceinline__ float fsigmoid(float x) {   // 1/(1+e^-x), fast
    return 1.0f / (1.0f + __expf(-x));
}
// tanh-form gelu via sigmoid: gelu(x) ~= x * sigmoid(1.595769122*(x+0.044715x^3))
__device__ __forceinline__ float fgelu(float x) {
    return x * fsigmoid(1.595769122f * fmaf(0.044715f * x * x, x, x));
}

// merged fp32 -> bf16 conversion for all 4 arrays, 4-wide, grid-stride
__global__ void cvt_all_kernel(const float* __restrict__ s0, unsigned short* __restrict__ d0, int n0,
                               const float* __restrict__ s1, unsigned short* __restrict__ d1, int n1,
                               const float* __restrict__ s2, unsigned short* __restrict__ d2, int n2,
                               const float* __restrict__ s3, unsigned short* __restrict__ d3, int n3) {
    int i = blockIdx.x * 256 + threadIdx.x;
    const int stride = gridDim.x * 256;
    const int total = n0 + n1 + n2 + n3;
    for (; i < total; i += stride) {
        const float* s; unsigned short* d; int j = i;
        if (j < n0)              { s = s0; d = d0; }
        else if ((j -= n0) < n1) { s = s1; d = d1; }
        else if ((j -= n1) < n2) { s = s2; d = d2; }
        else                     { j -= n2; s = s3; d = d3; }
        float4 v = ((const float4*)s)[j];
        ushort4 o;
        o.x = f2bf(v.x); o.y = f2bf(v.y); o.z = f2bf(v.z); o.w = f2bf(v.w);
        ((ushort4*)d)[j] = o;
    }
}

// sp8[h] = -8 * softplus(forget_base[h])
__global__ void sp8_kernel(const float* __restrict__ fb, float* __restrict__ sp8) {
    int h = blockIdx.x * 256 + threadIdx.x;
    if (h < HID) sp8[h] = -8.0f * log1pf(expf(fb[h]));
}

// diagnostic: plant a constant in d_out so absmax reports ws_size (MiB)
__global__ void plant_kernel(float* __restrict__ out, int n, float val) {
    int i = blockIdx.x * 256 + threadIdx.x;
    int stride = gridDim.x * 256;
    for (; i < n; i += stride) out[i] = val;
}

// async global->LDS, 16B per lane (global_load_lds_dwordx4)
__device__ __forceinline__ void gload_lds16(const unsigned short* g, unsigned short* l) {
    __builtin_amdgcn_global_load_lds(
        (const __attribute__((address_space(1))) void*)g,
        (__attribute__((address_space(3))) void*)l, 16, 0, 0);
}

// XCD-aware swizzle: give each XCD (id%8) a contiguous tile range.
__device__ __forceinline__ void xcd_swizzle(int& bx, int& by) {
    const int gx = gridDim.x;
    const int nblk = gx * gridDim.y;
    int id = by * gx + bx;
    id = (id & 7) * (nblk >> 3) + (id >> 3);
    bx = id % gx;
    by = id / gx;
}

// C[M,N] = A[M,K] (bf16 row-major) * B[N,K]^T (bf16 row-major)
// 128x128 tile, BK=64, 4 waves 2x2, 4x4 frags of 16x16x32 MFMA per wave.
// EPI: 0 = fp32 C; 1 = bf16 C.
template <int EPI>
__launch_bounds__(256, 2)
__global__ void gemm_bt(const unsigned short* __restrict__ A,
                        const unsigned short* __restrict__ B,
                        void* __restrict__ Cv, int M, int N, int K) {
    __shared__ unsigned short As[128 * 64];
    __shared__ unsigned short Bs[128 * 64];

    const int tid  = threadIdx.x;
    const int lane = tid & 63;
    const int wv   = tid >> 6;
    const int quad = lane >> 4;
    const int l15  = lane & 15;
    int bx = blockIdx.x, by = blockIdx.y;
    xcd_swizzle(bx, by);
    const long arow = (long)by * 128;
    const long brow = (long)bx * 128;
    const int  wr   = (wv >> 1) * 64;
    const int  wc   = (wv & 1) * 64;

    f32x4 acc[4][4];
#pragma unroll
    for (int i = 0; i < 4; ++i)
#pragma unroll
        for (int j = 0; j < 4; ++j) acc[i][j] = (f32x4){0.f, 0.f, 0.f, 0.f};

    for (int k0 = 0; k0 < K; k0 += 64) {
        __syncthreads();
#pragma unroll
        for (int it = 0; it < 4; ++it) {
            const int ebase = it * 2048 + wv * 512;   // wave-uniform LDS elem base
            const int e = ebase + lane * 8;
            const int r = e >> 6, c = e & 63;
            gload_lds16(A + (arow + r) * K + k0 + c, As + ebase);
            gload_lds16(B + (brow + r) * K + k0 + c, Bs + ebase);
        }
        __syncthreads();

#pragma unroll
        for (int kk = 0; kk < 2; ++kk) {
            bf16x8 af[4], bfr[4];
#pragma unroll
            for (int i = 0; i < 4; ++i)
                af[i] = *(const bf16x8*)(As + (wr + i * 16 + l15) * 64 + kk * 32 + quad * 8);
#pragma unroll
            for (int j = 0; j < 4; ++j)
                bfr[j] = *(const bf16x8*)(Bs + (wc + j * 16 + l15) * 64 + kk * 32 + quad * 8);
#pragma unroll
            for (int i = 0; i < 4; ++i)
#pragma unroll
                for (int j = 0; j < 4; ++j)
                    acc[i][j] = __builtin_amdgcn_mfma_f32_16x16x32_bf16(
                        af[i], bfr[j], acc[i][j], 0, 0, 0);
        }
    }

    // C/D layout: col=lane&15, row=quad*4+reg (m89/m91-verified)
#pragma unroll
    for (int i = 0; i < 4; ++i)
#pragma unroll
        for (int j = 0; j < 4; ++j)
#pragma unroll
            for (int r = 0; r < 4; ++r) {
                const long row = arow + wr + i * 16 + quad * 4 + r;
                const long col = brow + wc + j * 16 + l15;
                const float v = acc[i][j][r];
                if (EPI == 0)
                    ((float*)Cv)[row * N + col] = v;
                else
                    ((unsigned short*)Cv)[row * N + col] = f2bf(v);
            }
}

// GEMM2 fused with gates: forget tile (B rows h) + input tile (B rows h+HID);
// RG-LRU gate math in-register; stores PACKED (log_alpha | xs<<16), full-line
// stores. grid (HID/128, M_TOT/128), block 256.
// NOTE: (256,2) only — (256,3) forces VGPR cap -> spill -> 3.5 GB scratch
// traffic, 793 us (measured R8). Do not raise.
__launch_bounds__(256, 2)
__global__ void gemm_gates(const unsigned short* __restrict__ A,   // xh bf16 [M,HID]
                           const unsigned short* __restrict__ B,   // W_gates bf16 [G2,HID]
                           const float* __restrict__ sp8,          // -8*softplus(fb)
                           const float* __restrict__ bg,
                           unsigned* __restrict__ laxs) {          // [M,HID] packed
    const int K = HID;
    __shared__ unsigned short As[128 * 64];
    __shared__ unsigned short Bf[128 * 64];
    __shared__ unsigned short Bi[128 * 64];

    const int tid  = threadIdx.x;
    const int lane = tid & 63;
    const int wv   = tid >> 6;
    const int quad = lane >> 4;
    const int l15  = lane & 15;
    int bx = blockIdx.x, by = blockIdx.y;
    xcd_swizzle(bx, by);
    const long arow = (long)by * 128;
    const int  c0   = bx * 128;   // channel base
    const int  wr   = (wv >> 1) * 64;
    const int  wc   = (wv & 1) * 64;

    f32x4 accF[4][4], accI[4][4];
#pragma unroll
    for (int i = 0; i < 4; ++i)
#pragma unroll
        for (int j = 0; j < 4; ++j) {
            accF[i][j] = (f32x4){0.f, 0.f, 0.f, 0.f};
            accI[i][j] = (f32x4){0.f, 0.f, 0.f, 0.f};
        }

    for (int k0 = 0; k0 < K; k0 += 64) {
        __syncthreads();
#pragma unroll
        for (int it = 0; it < 4; ++it) {
            const int ebase = it * 2048 + wv * 512;
            const int e = ebase + lane * 8;
            const int r = e >> 6, c = e & 63;
            gload_lds16(A + (arow + r) * K + k0 + c, As + ebase);
            gload_lds16(B + (long)(c0 + r) * K + k0 + c, Bf + ebase);
            gload_lds16(B + (long)(HID + c0 + r) * K + k0 + c, Bi + ebase);
        }
        __syncthreads();

#pragma unroll
        for (int kk = 0; kk < 2; ++kk) {
            bf16x8 af[4], bff[4], bfi[4];
#pragma unroll
            for (int i = 0; i < 4; ++i)
                af[i] = *(const bf16x8*)(As + (wr + i * 16 + l15) * 64 + kk * 32 + quad * 8);
#pragma unroll
            for (int j = 0; j < 4; ++j) {
                bff[j] = *(const bf16x8*)(Bf + (wc + j * 16 + l15) * 64 + kk * 32 + quad * 8);
                bfi[j] = *(const bf16x8*)(Bi + (wc + j * 16 + l15) * 64 + kk * 32 + quad * 8);
            }
#pragma unroll
            for (int i = 0; i < 4; ++i)
#pragma unroll
                for (int j = 0; j < 4; ++j) {
                    accF[i][j] = __builtin_amdgcn_mfma_f32_16x16x32_bf16(
                        af[i], bff[j], accF[i][j], 0, 0, 0);
                    accI[i][j] = __builtin_amdgcn_mfma_f32_16x16x32_bf16(
                        af[i], bfi[j], accI[i][j], 0, 0, 0);
                }
        }
    }

    // epilogue: hoist per-h params (4 h per thread), i-outer, full-line stores
    float s8v[4], bgfv[4], bgiv[4];
    int hv[4];
#pragma unroll
    for (int j = 0; j < 4; ++j) {
        hv[j]   = c0 + wc + j * 16 + l15;
        s8v[j]  = sp8[hv[j]];
        bgfv[j] = bg[hv[j]];
        bgiv[j] = bg[HID + hv[j]];
    }
#pragma unroll
    for (int i = 0; i < 4; ++i)
#pragma unroll
        for (int r = 0; r < 4; ++r) {
            const long row = arow + wr + i * 16 + quad * 4 + r;
#pragma unroll
            for (int j = 0; j < 4; ++j) {
                const float f  = accF[i][j][r] + bgfv[j];
                const float ip = accI[i][j][r] + bgiv[j];
                const float xh = bf2f(A[row * HID + hv[j]]);
                const float la    = s8v[j] * fsigmoid(f);   // log(alpha)
                const float alpha = __expf(la);
                const float beta  = sqrtf(1.0f - alpha * alpha + 1e-6f);
                const float xs    = beta * fsigmoid(ip) * xh;
                laxs[row * HID + hv[j]] =
                    (unsigned)f2bf(la) | ((unsigned)f2bf(xs) << 16);
            }
        }
}

// Fused causal depthwise conv (K=4) + gelu(gate), 2 channels/thread, packed
// 4 B IO. u layout [M, G2] bf16: cols 0..HID-1 gate, HID..G2-1 xh-pre.
// grid (HID/512, M_TOT), block 256
__global__ void conv_gate_kernel(const unsigned short* __restrict__ u,
                                 const float* __restrict__ conv_w,
                                 const float* __restrict__ conv_b,
                                 unsigned short* __restrict__ xhbf,
                                 unsigned short* __restrict__ ggbf) {
    const int hp = blockIdx.x * 256 + threadIdx.x;    // channel pair
    const int h0 = hp * 2, h1 = h0 + 1;
    const int m = blockIdx.y;
    const int t = m & (T_SEQ - 1);
    const unsigned* u2 = (const unsigned*)u;
    const size_t rowb = (size_t)m * (G2 / 2);
    float a0 = conv_b[h0], a1 = conv_b[h1];
    {
        const unsigned v = u2[rowb + HID / 2 + hp];
        a0 = fmaf(conv_w[h0 * 4 + 3], bf2f((unsigned short)(v & 0xffff)), a0);
        a1 = fmaf(conv_w[h1 * 4 + 3], bf2f((unsigned short)(v >> 16)), a1);
    }
    if (t >= 1) {
        const unsigned v = u2[rowb - G2 / 2 + HID / 2 + hp];
        a0 = fmaf(conv_w[h0 * 4 + 2], bf2f((unsigned short)(v & 0xffff)), a0);
        a1 = fmaf(conv_w[h1 * 4 + 2], bf2f((unsigned short)(v >> 16)), a1);
    }
    if (t >= 2) {
        const unsigned v = u2[rowb - G2 + HID / 2 + hp];
        a0 = fmaf(conv_w[h0 * 4 + 1], bf2f((unsigned short)(v & 0xffff)), a0);
        a1 = fmaf(conv_w[h1 * 4 + 1], bf2f((unsigned short)(v >> 16)), a1);
    }
    if (t >= 3) {
        const unsigned v = u2[rowb - 3 * (G2 / 2) + HID / 2 + hp];
        a0 = fmaf(conv_w[h0 * 4 + 0], bf2f((unsigned short)(v & 0xffff)), a0);
        a1 = fmaf(conv_w[h1 * 4 + 0], bf2f((unsigned short)(v >> 16)), a1);
    }
    const size_t oidx = (size_t)m * (HID / 2) + hp;
    ((unsigned*)xhbf)[oidx] = (unsigned)f2bf(a0) | ((unsigned)f2bf(a1) << 16);
    const unsigned g = u2[rowb + hp];
    const float g0 = fgelu(bf2f((unsigned short)(g & 0xffff)));
    const float g1 = fgelu(bf2f((unsigned short)(g >> 16)));
    ((unsigned*)ggbf)[oidx] = (unsigned)f2bf(g0) | ((unsigned)f2bf(g1) << 16);
}

// ---- chunked parallel scan (packed laxs input) ----
__global__ void scan_local_kernel(const unsigned* __restrict__ laxs,
                                  float* __restrict__ Pbuf,
                                  float* __restrict__ Ebuf) {
    const int hp = blockIdx.x * 256 + threadIdx.x;
    const int nc = blockIdx.y;
    const int n = nc >> 4, c = nc & (NCH - 1);
    const uint2* l2 = (const uint2*)laxs;
    size_t idx = (((size_t)n * T_SEQ + (size_t)c * CHUNK) * HID >> 1) + hp;
    float P0 = 1.f, P1 = 1.f, h0 = 0.f, h1 = 0.f;
#pragma unroll 4
    for (int t = 0; t < CHUNK; ++t, idx += HID / 2) {
        const uint2 w = l2[idx];
        const float a0 = __expf(bf2f((unsigned short)(w.x & 0xffff)));
        const float a1 = __expf(bf2f((unsigned short)(w.y & 0xffff)));
        P0 *= a0; P1 *= a1;
        h0 = fmaf(a0, h0, bf2f((unsigned short)(w.x >> 16)));
        h1 = fmaf(a1, h1, bf2f((unsigned short)(w.y >> 16)));
    }
    const size_t cidx = (size_t)nc * (HID / 2) + hp;
    ((float2*)Pbuf)[cidx] = make_float2(P0, P1);
    ((float2*)Ebuf)[cidx] = make_float2(h0, h1);
}

__global__ void scan_carry_kernel(const float* __restrict__ Pbuf,
                                  const float* __restrict__ Ebuf,
                                  float* __restrict__ Cbuf) {
    const int hp = blockIdx.x * 256 + threadIdx.x;
    const int n = blockIdx.y;
    float c0 = 0.f, c1 = 0.f;
    for (int c = 0; c < NCH; ++c) {
        const size_t cidx = (size_t)(n * NCH + c) * (HID / 2) + hp;
        const float2 P = ((const float2*)Pbuf)[cidx];
        const float2 E = ((const float2*)Ebuf)[cidx];
        ((float2*)Cbuf)[cidx] = make_float2(c0, c1);
        c0 = fmaf(P.x, c0, E.x);
        c1 = fmaf(P.y, c1, E.y);
    }
}

__global__ void scan_apply_kernel(const unsigned* __restrict__ laxs,
                                  const unsigned short* __restrict__ ggbf,
                                  const float* __restrict__ Cbuf,
                                  unsigned short* __restrict__ vbf) {
    const int hp = blockIdx.x * 256 + threadIdx.x;
    const int nc = blockIdx.y;
    const int n = nc >> 4, c = nc & (NCH - 1);
    const float2 cr = ((const float2*)Cbuf)[(size_t)nc * (HID / 2) + hp];
    float h0 = cr.x, h1 = cr.y;
    const uint2* l2 = (const uint2*)laxs;
    const unsigned* gg2 = (const unsigned*)ggbf;
    unsigned* v2 = (unsigned*)vbf;
    size_t idx = (((size_t)n * T_SEQ + (size_t)c * CHUNK) * HID >> 1) + hp;
#pragma unroll 4
    for (int t = 0; t < CHUNK; ++t, idx += HID / 2) {
        const uint2 w = l2[idx];
        const unsigned gg = gg2[idx];
        const float a0 = __expf(bf2f((unsigned short)(w.x & 0xffff)));
        const float a1 = __expf(bf2f((unsigned short)(w.y & 0xffff)));
        h0 = fmaf(a0, h0, bf2f((unsigned short)(w.x >> 16)));
        h1 = fmaf(a1, h1, bf2f((unsigned short)(w.y >> 16)));
        const float v0 = bf2f((unsigned short)(gg & 0xffff)) * h0;
        const float v1 = bf2f((unsigned short)(gg >> 16)) * h1;
        v2[idx] = (unsigned)f2bf(v0) | ((unsigned)f2bf(v1) << 16);
    }
}

extern "C" void kernel_launch(void* const* d_in, const int* in_sizes, int n_in,
                              void* d_out, int out_size, void* d_ws, size_t ws_size,
                              hipStream_t stream) {
    const float* x     = (const float*)d_in[0];
    const float* Win   = (const float*)d_in[1];
    const float* convw = (const float*)d_in[2];
    const float* convb = (const float*)d_in[3];
    const float* Wg    = (const float*)d_in[4];
    const float* bg    = (const float*)d_in[5];
    const float* fb    = (const float*)d_in[6];
    const float* Wo    = (const float*)d_in[7];
    float* out = (float*)d_out;

    // ---- workspace layout (~245 MiB, liveness-aliased; ws ~256 MiB) ----
    const size_t SZ_WG  = (size_t)G2 * HID * 2;     //  9.0 MiB
    const size_t SZ_WO  = (size_t)DIMX * HID * 2;   //  3.0 MiB
    const size_t SZ_E   = (size_t)M_TOT * G2 * 2;   // 96.0 MiB  ubf -> laxs
    const size_t SZ_F   = (size_t)M_TOT * HID * 2;  // 48.0 MiB  xhbf -> vbf
    const size_t SZ_G   = (size_t)M_TOT * HID * 2;  // 48.0 MiB  ggbf
    const size_t SZ_WI  = (size_t)G2 * DIMX * 2;    //  6.0 MiB
    const size_t SZ_X   = (size_t)M_TOT * DIMX * 2; // 32.0 MiB
    const size_t SZ_S   = (size_t)N_BATCH * NCH * HID * 4;  // 0.75 MiB each
    const size_t SZ_SP  = (size_t)HID * 4;
    const size_t need = SZ_WG + SZ_WO + SZ_E + SZ_F + SZ_G + SZ_WI + SZ_X
                        + 3 * SZ_S + SZ_SP;

    if (ws_size < need) {
        plant_kernel<<<1024, 256, 0, stream>>>(out, M_TOT * DIMX,
                                               (float)(ws_size >> 20));
        return;
    }

    char* ws = (char*)d_ws;
    unsigned short* wgbf = (unsigned short*)(ws);
    unsigned short* wobf = (unsigned short*)(ws + SZ_WG);
    char*           rE   = ws + SZ_WG + SZ_WO;
    unsigned short* ubf  = (unsigned short*)rE;                    // GEMM1 out [M,G2]
    unsigned*       laxs = (unsigned*)rE;                          // gemm_gates out (packed)
    unsigned short* xhbf = (unsigned short*)(rE + SZ_E);           // conv out
    unsigned short* vbf  = xhbf;                                   // scan out (aliases)
    unsigned short* ggbf = (unsigned short*)(rE + SZ_E + SZ_F);    // gelu(gate)
    unsigned short* wibf = (unsigned short*)(rE + SZ_E + SZ_F + SZ_G);
    unsigned short* xbf  = (unsigned short*)(rE + SZ_E + SZ_F + SZ_G + SZ_WI);
    float*          Pbuf = (float*)(rE + SZ_E + SZ_F + SZ_G + SZ_WI + SZ_X);
    float*          Ebuf = (float*)((char*)Pbuf + SZ_S);
    float*          Cbuf = (float*)((char*)Pbuf + 2 * SZ_S);
    float*          sp8  = (float*)((char*)Pbuf + 3 * SZ_S);

    // 1) bf16 casts (single merged launch) + sp8 precompute
    cvt_all_kernel<<<2048, 256, 0, stream>>>(
        x, xbf, M_TOT * DIMX / 4,
        Win, wibf, G2 * DIMX / 4,
        Wg, wgbf, G2 * HID / 4,
        Wo, wobf, DIMX * HID / 4);
    sp8_kernel<<<(HID + 255) / 256, 256, 0, stream>>>(fb, sp8);

    // 2) GEMM1: u = x @ W_in^T  [16384 x 3072] -> bf16
    gemm_bt<1><<<dim3(G2 / 128, M_TOT / 128), 256, 0, stream>>>(
        xbf, wibf, ubf, M_TOT, G2, DIMX);

    // 3) fused conv + gelu(gate)
    conv_gate_kernel<<<dim3(HID / 512, M_TOT), 256, 0, stream>>>(
        ubf, convw, convb, xhbf, ggbf);

    // 4) GEMM2 fused gates -> packed (log_alpha | xs) (overwrites ubf)
    gemm_gates<<<dim3(HID / 128, M_TOT / 128), 256, 0, stream>>>(
        xhbf, wgbf, sp8, bg, laxs);

    // 5) chunked parallel linear recurrence + gelu(gate) multiply
    scan_local_kernel<<<dim3(HID / 512, N_BATCH * NCH), 256, 0, stream>>>(
        laxs, Pbuf, Ebuf);
    scan_carry_kernel<<<dim3(HID / 512, N_BATCH), 256, 0, stream>>>(
        Pbuf, Ebuf, Cbuf);
    scan_apply_kernel<<<dim3(HID / 512, N_BATCH * NCH), 256, 0, stream>>>(
        laxs, ggbf, Cbuf, vbf);

    // 6) GEMM3: out = v @ W_out^T -> fp32 into d_out
    gemm_bt<0><<<dim3(DIMX / 128, M_TOT / 128), 256, 0, stream>>>(
        vbf, wobf, out, M_TOT, DIMX, HID);

    (void)in_sizes; (void)n_in; (void)out_size;
}